// Round 12
// baseline (374.717 us; speedup 1.0000x reference)
//
#include <hip/hip_runtime.h>

typedef unsigned short u16;
typedef unsigned char u8;
typedef long i64;
typedef __attribute__((ext_vector_type(8))) short bf16x8;
typedef __attribute__((ext_vector_type(4))) float f32x4;
typedef __attribute__((ext_vector_type(8))) u16 u16x8;
typedef __attribute__((ext_vector_type(4))) u16 u16x4;
typedef __attribute__((ext_vector_type(4))) float f4;

#define DEVI static __device__ __forceinline__

DEVI u16 f2b(float f) { __bf16 h = (__bf16)f; return __builtin_bit_cast(u16, h); }
DEVI float b2f(u16 h) { unsigned u = ((unsigned)h) << 16; return __builtin_bit_cast(float, u); }

DEVI int pk8(float a, float b, float c, float d) {
  int w = __builtin_amdgcn_cvt_pk_fp8_f32(a, b, 0, false);
  return __builtin_amdgcn_cvt_pk_fp8_f32(c, d, w, true);
}

DEVI void gload16(const void* g, void* l) {
  __builtin_amdgcn_global_load_lds((const __attribute__((address_space(1))) void*)g,
                                   (__attribute__((address_space(3))) void*)l, 16, 0, 0);
}

// ---------------------------------------------------------------------------
// MERGED fused layer-1 big GEMMs, ONE 512-block launch, dispatch-order
// balanced. R12: pipeline depth 2 PAIRS -- 6 LDS buffers (150 KB), 3 A-reg
// banks (p%3 rotation, statically unrolled x3); loads for pair p+2 issued in
// super-step p, waited in SS p+2 (~2 SS ~ 7000 cyc >> 900 cyc HBM latency).
// vmcnt ladder from queue audit (per SS: 6 loads then 4 stores):
//   SS0 -> vmcnt(6); SS1 -> vmcnt(10); steady -> vmcnt(14); last -> vmcnt(0).
// Buffer reuse: L(p+2) targets bufs of pair p-1 whose compute finished before
// barrier p in program order on all waves -> race-free.
// NSS: x=24, y=12 (both %3==0). One barrier per 2 tiles.
// ---------------------------------------------------------------------------
__global__ __launch_bounds__(1024)
void gemmF_k(const float* __restrict__ xA0, const float* __restrict__ xA1,
             const u8* __restrict__ xB0, const u8* __restrict__ xB1,
             u8* __restrict__ xA0f8, u8* __restrict__ xA1f8,
             int xK0, int xK1, int xL0, int xL1, u16* __restrict__ xC, size_t xMN,
             const float* __restrict__ yA0, const float* __restrict__ yA1,
             const u8* __restrict__ yB0, const u8* __restrict__ yB1,
             u8* __restrict__ yA0f8, u8* __restrict__ yA1f8,
             int yK0, int yK1, int yL0, int yL1, u16* __restrict__ yC, size_t yMN)
{
  constexpr int BM = 128, BK = 64;
  constexpr int LDA = 72;
  constexpr int ASZ = BM * LDA;     // 9216
  constexpr int BSZ = 256 * BK;     // 16384
  constexpr int BUFSZ = ASZ + BSZ;  // 25600
  constexpr float SADJ = 8192.f;
  __shared__ __align__(16) u8 lds[6 * BUFSZ];   // 150 KiB -> 1 block/CU

  const int tid = threadIdx.x, lane = tid & 63, wave = tid >> 6;
  const int wm = (wave >> 2) * 32, wn = (wave & 3) * 64;   // 4x4 wave grid
  const int lgrp = lane >> 4, lrow = lane & 15;

  const int flat = blockIdx.x;                // 0..511

  const float *A0, *A1; const u8 *B0, *B1; u8 *A0f8, *A1f8;
  int K0, K1, L0, L1; u16* Cout; size_t MN; int m0, z;
  if (flat < 256) {                           // round 1: x on ALL CUs
    const int s = ((flat & 7) << 5) | (flat >> 3);   // XCD-chunked within x
    A0=xA0; A1=xA1; B0=xB0; B1=xB1; A0f8=xA0f8; A1f8=xA1f8;
    K0=xK0; K1=xK1; L0=xL0; L1=xL1; Cout=xC; MN=xMN;
    m0 = (s & 63) * BM; z = s >> 6;           // gy=64, z 0..3 (KSx=4)
  } else {                                    // round 2: y on ALL CUs
    const int f2 = flat - 256;
    const int s = ((f2 & 7) << 5) | (f2 >> 3);
    A0=yA0; A1=yA1; B0=yB0; B1=yB1; A0f8=yA0f8; A1f8=yA1f8;
    K0=yK0; K1=yK1; L0=yL0; L1=yL1; Cout=yC; MN=yMN;
    m0 = (s & 31) * BM; z = s >> 5;           // gy=32, z 0..7 (KSy=8)
  }

  const int nt0 = L0 >> 6, NT = nt0 + (L1 >> 6);   // 48 (x) / 24 (y)
  const int NSS = NT >> 1;                         // 24 / 12, both %3==0

  const int r0 = tid >> 4;           // 0..63
  const int cf = (tid & 15) << 2;    // 0..60

  f32x4 acc[2][4];
#pragma unroll
  for (int m = 0; m < 2; ++m)
#pragma unroll
    for (int n = 0; n < 4; ++n) acc[m][n] = (f32x4){0.f, 0.f, 0.f, 0.f};

  f4 bk0[4], bk1[4], bk2[4];         // 3 pair-banks: [tile0 j0,j1, tile1 j0,j1]
  int pw0[2], pw1[2];                // packed fp8 words for the current pair

  auto tileinfo = [&](int t, const float*& Ap, const u8*& Bp, u8*& Af8, int& Kj, int& kk) {
    if (t < nt0) { Ap = A0; Bp = B0; Af8 = A0f8; Kj = K0; kk = z * L0 + (t << 6); }
    else         { Ap = A1; Bp = B1; Af8 = A1f8; Kj = K1; kk = z * L1 + ((t - nt0) << 6); }
  };

  auto loadB = [&](int t) {
    const float* Ap; const u8* Bp; u8* Af8; int Kj, kk;
    tileinfo(t, Ap, Bp, Af8, Kj, kk);
    u8* sB = &lds[(t % 6) * BUFSZ] + ASZ;
    const int off = tid * 16;
    const int r = off >> 6, c = off & 63;
    gload16(Bp + (size_t)r * Kj + kk + (c ^ (((r >> 1) & 3) << 4)), sB + off);
  };

  // issue the 6 VM loads of pair p: A(2p)x2, B(2p), A(2p+1)x2, B(2p+1)
  auto loadPair = [&](int p, f4 (&bk)[4]) {
    const int t0 = 2 * p;
#pragma unroll
    for (int h = 0; h < 2; ++h) {
      const int t = t0 + h;
      const float* Ap; const u8* Bp; u8* Af8; int Kj, kk;
      tileinfo(t, Ap, Bp, Af8, Kj, kk);
#pragma unroll
      for (int j = 0; j < 2; ++j) {
        const int rr = j * 64 + r0;
        bk[h * 2 + j] = __builtin_nontemporal_load(
            (const f4*)(Ap + (size_t)(m0 + rr) * Kj + kk + cf));
      }
      loadB(t);
    }
  };

  auto writeLDS = [&](int t, f4* r, int (&pw)[2]) {   // cvt + ds_write only
    u8* sA = &lds[(t % 6) * BUFSZ];
#pragma unroll
    for (int j = 0; j < 2; ++j) {
      const int rr = j * 64 + r0;
      pw[j] = pk8(r[j][0] * SADJ, r[j][1] * SADJ, r[j][2] * SADJ, r[j][3] * SADJ);
      *(int*)&sA[rr * LDA + cf] = pw[j];
    }
  };

  auto storeCopy = [&](int t, int (&pw)[2]) {         // fp8 side-copy stores
    const float* Ap; const u8* Bp; u8* Af8; int Kj, kk;
    tileinfo(t, Ap, Bp, Af8, Kj, kk);
#pragma unroll
    for (int j = 0; j < 2; ++j) {
      const int rr = j * 64 + r0;
      *(int*)(Af8 + (size_t)(m0 + rr) * Kj + kk + cf) = pw[j];
    }
  };

  auto compute = [&](int t) {
    const u8* sA = &lds[(t % 6) * BUFSZ];
    const u8* sB = sA + ASZ;
    __builtin_amdgcn_s_setprio(1);
#pragma unroll
    for (int ks = 0; ks < 2; ++ks) {
      i64 a[2], b[4];
#pragma unroll
      for (int m = 0; m < 2; ++m) {
        const int r = wm + m * 16 + lrow;
        a[m] = *(const i64*)&sA[r * LDA + ks * 32 + lgrp * 8];
      }
#pragma unroll
      for (int n = 0; n < 4; ++n) {
        const int r = wn + n * 16 + lrow;
        b[n] = *(const i64*)&sB[r * BK + ((ks * 32 + lgrp * 8) ^ (((r >> 1) & 3) << 4))];
      }
#pragma unroll
      for (int m = 0; m < 2; ++m)
#pragma unroll
        for (int n = 0; n < 4; ++n)
          acc[m][n] = __builtin_amdgcn_mfma_f32_16x16x32_fp8_fp8(a[m], b[n], acc[m][n], 0, 0, 0);
    }
    __builtin_amdgcn_s_setprio(0);
  };

  // superstep p: wait -> writeLDS(pair p from cur) -> lgkm+barrier ->
  // loadPair(p+2 into nxt) -> storeCopy(pair p) -> compute(pair p)
  auto superstep = [&](int p, f4 (&cur)[4], f4 (&nxt)[4]) {
    const int t = 2 * p;
    if (p == NSS - 1)      asm volatile("s_waitcnt vmcnt(0)"  ::: "memory");
    else if (p == 0)       asm volatile("s_waitcnt vmcnt(6)"  ::: "memory");
    else if (p == 1)       asm volatile("s_waitcnt vmcnt(10)" ::: "memory");
    else                   asm volatile("s_waitcnt vmcnt(14)" ::: "memory");
    writeLDS(t,     &cur[0], pw0);
    writeLDS(t + 1, &cur[2], pw1);
    asm volatile("s_waitcnt lgkmcnt(0)" ::: "memory");
    asm volatile("s_barrier" ::: "memory");
    if (p + 2 < NSS) loadPair(p + 2, nxt);    // loads BEFORE stores
    storeCopy(t, pw0);
    storeCopy(t + 1, pw1);
    compute(t);
    compute(t + 1);
  };

  // prologue: pairs 0 and 1 in flight (12 loads)
  loadPair(0, bk0);
  loadPair(1, bk1);

  for (int p = 0; p < NSS; p += 3) {          // NSS % 3 == 0
    superstep(p,     bk0, bk2);
    superstep(p + 1, bk1, bk0);
    superstep(p + 2, bk2, bk1);
  }

  u16* Cp = Cout + (size_t)z * MN;
#pragma unroll
  for (int n = 0; n < 4; ++n) {
    const int c = wn + n * 16 + lrow;
#pragma unroll
    for (int m = 0; m < 2; ++m) {
      const int rb = m0 + wm + m * 16 + lgrp * 4;
#pragma unroll
      for (int q = 0; q < 4; ++q)
        Cp[(size_t)(rb + q) * 256 + c] = f2b(acc[m][n][q]);
    }
  }
}

// ---------------------------------------------------------------------------
// MERGED fp8 layer-2 big GEMMs, ONE 1024-block launch (R10, unchanged).
// ---------------------------------------------------------------------------
__global__ __launch_bounds__(256)
void gemm8_k(const u8* __restrict__ xA0, const u8* __restrict__ xA1,
             const u8* __restrict__ xB0, const u8* __restrict__ xB1,
             int xK0, int xK1, int xL0, int xL1, u16* __restrict__ xC, size_t xMN,
             const u8* __restrict__ yA0, const u8* __restrict__ yA1,
             const u8* __restrict__ yB0, const u8* __restrict__ yB1,
             int yK0, int yK1, int yL0, int yL1, u16* __restrict__ yC, size_t yMN)
{
  constexpr int BM = 128, BK = 128, BN = 64;
  constexpr int MR = 4, NR = 2;
  constexpr int ASZ = BM * BK, BSZ = BN * BK;
  __shared__ __align__(16) u8 lds[3 * (ASZ + BSZ)];

  const int tid = threadIdx.x, lane = tid & 63, wave = tid >> 6;
  const int wm = (wave >> 1) * 64, wn = (wave & 1) * 32;
  const int lgrp = lane >> 4, lrow = lane & 15;

  const int flat = blockIdx.x;                // 0..1023

  const u8 *A0, *A1, *B0, *B1; int K0, K1, L0, L1; u16* Cw; size_t MN;
  int m0, z;
  if (flat < 512) {
    const int s = ((flat & 7) << 6) | (flat >> 3);
    A0=xA0; A1=xA1; B0=xB0; B1=xB1; K0=xK0; K1=xK1; L0=xL0; L1=xL1; Cw=xC; MN=xMN;
    m0 = (s & 63) * BM; z = s >> 6;
  } else {
    const int f2 = flat - 512;
    const int s = ((f2 & 7) << 6) | (f2 >> 3);
    A0=yA0; A1=yA1; B0=yB0; B1=yB1; K0=yK0; K1=yK1; L0=yL0; L1=yL1; Cw=yC; MN=yMN;
    m0 = (s & 31) * BM; z = s >> 5;
  }

  const int nt0 = L0 >> 7, NT = nt0 + (L1 >> 7);

  f32x4 acc[MR][NR];
#pragma unroll
  for (int m = 0; m < MR; ++m)
#pragma unroll
    for (int n = 0; n < NR; ++n) acc[m][n] = (f32x4){0.f, 0.f, 0.f, 0.f};

  auto stage = [&](int buf, int t) {
    const u8* Ap; const u8* Bp; int Kj, kk;
    if (t < nt0) { Ap = A0; Bp = B0; Kj = K0; kk = z * L0 + (t << 7); }
    else         { Ap = A1; Bp = B1; Kj = K1; kk = z * L1 + ((t - nt0) << 7); }
    u8* sA = &lds[buf * (ASZ + BSZ)];
    u8* sB = sA + ASZ;
#pragma unroll
    for (int i = 0; i < ASZ / 4096; ++i) {
      const int off = i * 4096 + tid * 16;
      const int r = off >> 7, c = off & 127;
      gload16(Ap + (size_t)(m0 + r) * Kj + kk + (c ^ ((r & 7) << 4)), sA + off);
    }
#pragma unroll
    for (int i = 0; i < BSZ / 4096; ++i) {
      const int off = i * 4096 + tid * 16;
      const int r = off >> 7, c = off & 127;
      gload16(Bp + (size_t)r * Kj + kk + (c ^ ((r & 7) << 4)), sB + off);
    }
  };

  auto compute = [&](int buf) {
    const u8* sA = &lds[buf * (ASZ + BSZ)];
    const u8* sB = sA + ASZ;
    __builtin_amdgcn_s_setprio(1);
#pragma unroll
    for (int ks = 0; ks < 4; ++ks) {
      i64 a[MR], b[NR];
#pragma unroll
      for (int m = 0; m < MR; ++m) {
        const int r = wm + m * 16 + lrow;
        a[m] = *(const i64*)&sA[r * BK + ((ks * 32 + lgrp * 8) ^ ((r & 7) << 4))];
      }
#pragma unroll
      for (int n = 0; n < NR; ++n) {
        const int r = wn + n * 16 + lrow;
        b[n] = *(const i64*)&sB[r * BK + ((ks * 32 + lgrp * 8) ^ ((r & 7) << 4))];
      }
#pragma unroll
      for (int m = 0; m < MR; ++m)
#pragma unroll
        for (int n = 0; n < NR; ++n)
          acc[m][n] = __builtin_amdgcn_mfma_f32_16x16x32_fp8_fp8(a[m], b[n], acc[m][n], 0, 0, 0);
    }
    __builtin_amdgcn_s_setprio(0);
  };

  stage(0, 0);
  stage(1, 1);
  for (int t = 0; t < NT; ++t) {
    if (t + 1 < NT) asm volatile("s_waitcnt vmcnt(6)" ::: "memory");
    else            asm volatile("s_waitcnt vmcnt(0)" ::: "memory");
    asm volatile("s_barrier" ::: "memory");
    compute(t % 3);
    if (t + 2 < NT) stage((t + 2) % 3, t + 2);
  }

  u16* Cp = Cw + (size_t)z * MN;
#pragma unroll
  for (int n = 0; n < NR; ++n) {
    const int c = wn + n * 16 + lrow;
#pragma unroll
    for (int m = 0; m < MR; ++m) {
      const int rb = m0 + wm + m * 16 + lgrp * 4;
#pragma unroll
      for (int q = 0; q < 4; ++q)
        Cp[(size_t)(rb + q) * 64 + c] = f2b(acc[m][n][q]);
    }
  }
}

// ---------------------------------------------------------------------------
// MERGED dual-problem small GEMM (unchanged).
// ---------------------------------------------------------------------------
template<bool A_F32>
__global__ __launch_bounds__(256)
void gemmS_k(const void* Ax, const u16* Bx, int Kx, int ldcx, u8* Cx1, u8* Cx2,
             const void* Ay, const u16* By, int Ky, int ldcy, u8* Cy1, u8* Cy2,
             int ySplit, int nsplit, float sOut)
{
  constexpr int BM = 64, BN = 64, BK = 32, LD = 40;
  constexpr int MR = 2, NR = 2;
  __shared__ u16 sA[BM * LD];
  __shared__ u16 sB[BN * LD];

  const int tid  = threadIdx.x;
  const int lane = tid & 63;
  const int wave = tid >> 6;
  const int wm = (wave >> 1) * 32;
  const int wn = (wave &  1) * 32;

  const void* A0_; const u16* B0_; int K0, ldc; u8 *C1, *C2; int m0;
  if ((int)blockIdx.y < ySplit) {
    A0_ = Ax; B0_ = Bx; K0 = Kx; ldc = ldcx; C1 = Cx1; C2 = Cx2;
    m0 = blockIdx.y * BM;
  } else {
    A0_ = Ay; B0_ = By; K0 = Ky; ldc = ldcy; C1 = Cy1; C2 = Cy2;
    m0 = (blockIdx.y - ySplit) * BM;
  }
  const int n0 = blockIdx.x * BN;

  constexpr int TPRA = 256 / BM;
  constexpr int EPTA = 32 / TPRA;
  const int ar = tid / TPRA, ac = (tid % TPRA) * EPTA;
  const int br = ar, bc = ac;

  f32x4 acc[MR][NR];
#pragma unroll
  for (int m = 0; m < MR; ++m)
#pragma unroll
    for (int n = 0; n < NR; ++n) acc[m][n] = (f32x4){0.f, 0.f, 0.f, 0.f};

  const int lgrp = lane >> 4, lrow = lane & 15;

  for (int kk = 0; kk < K0; kk += BK) {
    if constexpr (A_F32) {
      const float* Ap = (const float*)A0_ + (size_t)(m0 + ar) * K0 + kk + ac;
      f4 v0 = ((const f4*)Ap)[0];
      f4 v1 = ((const f4*)Ap)[1];
      u16x8 h;
      h[0]=f2b(v0[0]); h[1]=f2b(v0[1]); h[2]=f2b(v0[2]); h[3]=f2b(v0[3]);
      h[4]=f2b(v1[0]); h[5]=f2b(v1[1]); h[6]=f2b(v1[2]); h[7]=f2b(v1[3]);
      *(u16x8*)&sA[ar * LD + ac] = h;
    } else {
      const u16* Ap = (const u16*)A0_ + (size_t)(m0 + ar) * K0 + kk + ac;
      *(u16x8*)&sA[ar * LD + ac] = *(const u16x8*)Ap;
    }
    {
      const u16* Bp = B0_ + (size_t)(n0 + br) * K0 + kk + bc;
      *(u16x8*)&sB[br * LD + bc] = *(const u16x8*)Bp;
    }
    __syncthreads();
    bf16x8 af[MR], bfr[NR];
#pragma unroll
    for (int m = 0; m < MR; ++m)
      af[m] = *(const bf16x8*)&sA[(wm + m * 16 + lrow) * LD + lgrp * 8];
#pragma unroll
    for (int n = 0; n < NR; ++n)
      bfr[n] = *(const bf16x8*)&sB[(wn + n * 16 + lrow) * LD + lgrp * 8];
#pragma unroll
    for (int m = 0; m < MR; ++m)
#pragma unroll
      for (int n = 0; n < NR; ++n)
        acc[m][n] = __builtin_amdgcn_mfma_f32_16x16x32_bf16(af[m], bfr[n], acc[m][n], 0, 0, 0);
    __syncthreads();
  }

#pragma unroll
  for (int n = 0; n < NR; ++n) {
    const int c = n0 + wn + n * 16 + lrow;
    u8* Cp = (c < nsplit) ? C1 : C2;
    const int cr = (c < nsplit) ? c : c - nsplit;
#pragma unroll
    for (int m = 0; m < MR; ++m) {
      const int rb = m0 + wm + m * 16 + lgrp * 4;
      int w = __builtin_amdgcn_cvt_pk_fp8_f32(acc[m][n][0] * sOut, acc[m][n][1] * sOut, 0, false);
      w = __builtin_amdgcn_cvt_pk_fp8_f32(acc[m][n][2] * sOut, acc[m][n][3] * sOut, w, true);
      *(int*)&Cp[(size_t)cr * ldc + rb] = w;
    }
  }
}

// ---------------------------------------------------------------------------
// bf16 GEMM for h_hat: sigmoid -> f32 row-major, nontemporal stores (unchanged).
// ---------------------------------------------------------------------------
__global__ __launch_bounds__(256)
void gemmH_k(const u16* A0_, const u16* B0_, int K0, float* Cout, int ldc)
{
  constexpr int BM = 128, BN = 128, BK = 32, LD = 40;
  constexpr int MR = 4, NR = 4;
  __shared__ u16 sA[BM * LD];
  __shared__ u16 sB[BN * LD];

  const int tid  = threadIdx.x;
  const int lane = tid & 63;
  const int wave = tid >> 6;
  const int wm = (wave >> 1) * 64;
  const int wn = (wave &  1) * 64;
  const int m0 = blockIdx.y * BM;
  const int n0 = blockIdx.x * BN;

  constexpr int TPRA = 2;
  constexpr int EPTA = 16;
  const int ar = tid / TPRA, ac = (tid % TPRA) * EPTA;

  f32x4 acc[MR][NR];
#pragma unroll
  for (int m = 0; m < MR; ++m)
#pragma unroll
    for (int n = 0; n < NR; ++n) acc[m][n] = (f32x4){0.f, 0.f, 0.f, 0.f};

  const int lgrp = lane >> 4, lrow = lane & 15;

  for (int kk = 0; kk < K0; kk += BK) {
    {
      const u16* Ap = A0_ + (size_t)(m0 + ar) * K0 + kk + ac;
      *(u16x8*)&sA[ar * LD + ac]     = ((const u16x8*)Ap)[0];
      *(u16x8*)&sA[ar * LD + ac + 8] = ((const u16x8*)Ap)[1];
      const u16* Bp = B0_ + (size_t)(n0 + ar) * K0 + kk + ac;
      *(u16x8*)&sB[ar * LD + ac]     = ((const u16x8*)Bp)[0];
      *(u16x8*)&sB[ar * LD + ac + 8] = ((const u16x8*)Bp)[1];
    }
    __syncthreads();
    bf16x8 af[MR], bfr[NR];
#pragma unroll
    for (int m = 0; m < MR; ++m)
      af[m] = *(const bf16x8*)&sA[(wm + m * 16 + lrow) * LD + lgrp * 8];
#pragma unroll
    for (int n = 0; n < NR; ++n)
      bfr[n] = *(const bf16x8*)&sB[(wn + n * 16 + lrow) * LD + lgrp * 8];
#pragma unroll
    for (int m = 0; m < MR; ++m)
#pragma unroll
      for (int n = 0; n < NR; ++n)
        acc[m][n] = __builtin_amdgcn_mfma_f32_16x16x32_bf16(af[m], bfr[n], acc[m][n], 0, 0, 0);
    __syncthreads();
  }

  float* Cp = Cout;
#pragma unroll
  for (int n = 0; n < NR; ++n) {
    const int c = n0 + wn + n * 16 + lrow;
#pragma unroll
    for (int m = 0; m < MR; ++m) {
      const int rb = m0 + wm + m * 16 + lgrp * 4;
#pragma unroll
      for (int q = 0; q < 4; ++q)
        __builtin_nontemporal_store(1.f / (1.f + __expf(-acc[m][n][q])),
                                    &Cp[(size_t)(rb + q) * ldc + c]);
    }
  }
}

// ---------------------------------------------------------------------------
// MERGED layer-1 combine (unchanged).
// ---------------------------------------------------------------------------
__global__ __launch_bounds__(256)
void combine1_k(const u16* __restrict__ partX, const u16* __restrict__ partY,
                int xBlocks, size_t MNx, size_t MNy, int KSx_, int KSy_,
                const float* bxa, const float* bxb, const float* ap,
                const float* bya, const float* byb, const float* bp,
                u16* x1, u16* y1, float invs)
{
  const u16* parts; size_t MN; int KS, nb, bid = blockIdx.x;
  const float *b0, *b1, *mixp; u16* out;
  if (bid < xBlocks) {
    parts = partX; MN = MNx; KS = KSx_; b0 = bxa; b1 = bxb; mixp = ap; out = x1; nb = xBlocks;
  } else {
    bid -= xBlocks;
    parts = partY; MN = MNy; KS = KSy_; b0 = bya; b1 = byb; mixp = bp; out = y1;
    nb = gridDim.x - xBlocks;
  }
  const float mix = *mixp;
  const size_t stride = (size_t)nb * 1024;
  for (size_t i = ((size_t)bid * 256 + threadIdx.x) * 4; i < MN; i += stride) {
    f4 s = {0.f, 0.f, 0.f, 0.f};
    for (int zz = 0; zz < KS; ++zz) {
      u16x4 pv = *(const u16x4*)&parts[(size_t)zz * MN + i];
#pragma unroll
      for (int q = 0; q < 4; ++q) s[q] += b2f(pv[q]);
    }
    const int c = (int)(i & 255);          // N = 256
    u16x4 o;
#pragma unroll
    for (int q = 0; q < 4; ++q) {
      float v = s[q] * invs + mix * b0[c + q] + (1.f - mix) * b1[c + q];
      v = v >= 0.f ? v : 0.2f * v;
      o[q] = f2b(v);
    }
    *(u16x4*)&out[i] = o;
  }
}

// ---------------------------------------------------------------------------
// FUSED layer-2 combine + log_softmax (unchanged).
// ---------------------------------------------------------------------------
__global__ __launch_bounds__(256)
void combine2_k(const u16* __restrict__ partX, const u16* __restrict__ partY,
                int xRowBlocks, size_t MNx, size_t MNy,
                const float* bxa, const float* bxb, const float* ap,
                const float* bya, const float* byb, const float* bp,
                u16* x2, u16* y2, float* xout, float invs)
{
  const int w = threadIdx.x >> 6, lane = threadIdx.x & 63;
  if ((int)blockIdx.x < xRowBlocks) {
    const int row = blockIdx.x * 4 + w;
    const float a = *ap;
    float s = 0.f;
#pragma unroll
    for (int z = 0; z < 8; ++z)
      s += b2f(partX[(size_t)z * MNx + (size_t)row * 64 + lane]);
    float v = s * invs + a * bxa[lane] + (1.f - a) * bxb[lane];
    v = v >= 0.f ? v : 0.2f * v;
    x2[(size_t)row * 64 + lane] = f2b(v);
    float m = v;
#pragma unroll
    for (int o = 32; o; o >>= 1) m = fmaxf(m, __shfl_xor(m, o));
    float t = __expf(v - m);
#pragma unroll
    for (int o = 32; o; o >>= 1) t += __shfl_xor(t, o);
    xout[(size_t)row * 64 + lane] = v - m - __logf(t);
  } else {
    const int row = ((int)blockIdx.x - xRowBlocks) * 4 + w;
    const float b = *bp;
    float s = 0.f;
#pragma unroll
    for (int z = 0; z < 16; ++z)
      s += b2f(partY[(size_t)z * MNy + (size_t)row * 64 + lane]);
    float v = s * invs + b * bya[lane] + (1.f - b) * byb[lane];
    v = v >= 0.f ? v : 0.2f * v;
    y2[(size_t)row * 64 + lane] = f2b(v);
  }
}

// Concatenated transposed scaled bf16 weights (unchanged)
__global__ __launch_bounds__(256)
void prep_w(const float* Wx1a, const float* Wx1b, const float* Wy1a, const float* Wy1b,
            const float* Wx2a, const float* Wx2b, const float* Wy2a, const float* Wy2b,
            u16* WtX, u16* WtY, u16* W2X, u16* W2Y,
            const float* ap, const float* bp)
{
  const int zz = blockIdx.z;
  const float a = *ap, b = *bp;
  const float* W; u16* O; int K, N, roff; float s;
  switch (zz) {
    case 0: W=Wx1a; O=WtX; K=512; N=256; roff=0;   s=a;      break;
    case 1: W=Wy1b; O=WtX; K=512; N=256; roff=256; s=1.f-b;  break;
    case 2: W=Wx1b; O=WtY; K=256; N=256; roff=0;   s=1.f-a;  break;
    case 3: W=Wy1a; O=WtY; K=256; N=256; roff=256; s=b;      break;
    case 4: W=Wx2a; O=W2X; K=256; N=64;  roff=0;   s=a;      break;
    case 5: W=Wy2b; O=W2X; K=256; N=64;  roff=64;  s=1.f-b;  break;
    case 6: W=Wx2b; O=W2Y; K=256; N=64;  roff=0;   s=1.f-a;  break;
    default:W=Wy2a; O=W2Y; K=256; N=64;  roff=64;  s=b;      break;
  }
  const int total = K * N;
  for (int i = blockIdx.x * 256 + threadIdx.x; i < total; i += gridDim.x * 256) {
    const int k = i / N, n = i - k * N;
    O[(size_t)(n + roff) * K + k] = f2b(W[i] * s);
  }
}

extern "C" void kernel_launch(void* const* d_in, const int* in_sizes, int n_in,
                              void* d_out, int out_size, void* d_ws, size_t ws_size,
                              hipStream_t stream)
{
  const float* hx1 = (const float*)d_in[0];
  const float* hx2 = (const float*)d_in[1];
  const float* x0  = (const float*)d_in[2];
  const float* hy1 = (const float*)d_in[3];
  const float* hy2 = (const float*)d_in[4];
  const float* y0  = (const float*)d_in[5];
  const float* alphap = (const float*)d_in[6];
  const float* betap  = (const float*)d_in[7];
  const float* Wx1a = (const float*)d_in[8];  const float* bx1a = (const float*)d_in[9];
  const float* Wx1b = (const float*)d_in[10]; const float* bx1b = (const float*)d_in[11];
  const float* Wx2a = (const float*)d_in[12]; const float* bx2a = (const float*)d_in[13];
  const float* Wx2b = (const float*)d_in[14]; const float* bx2b = (const float*)d_in[15];
  const float* Wy1a = (const float*)d_in[16]; const float* by1a = (const float*)d_in[17];
  const float* Wy1b = (const float*)d_in[18]; const float* by1b = (const float*)d_in[19];
  const float* Wy2a = (const float*)d_in[20]; const float* by2a = (const float*)d_in[21];
  const float* Wy2b = (const float*)d_in[22]; const float* by2b = (const float*)d_in[23];
  (void)in_sizes; (void)n_in; (void)out_size;

  constexpr int Nx = 8192, Ny = 4096, Fx = 512, Fy = 256, D1 = 256, C = 64;
  constexpr float SB1 = 16.f, SB2 = 256.f;
  constexpr float INV1 = 1.f / (8192.f * 16.f);
  constexpr float INV2 = 1.f / (8192.f * 256.f);
  constexpr int KSx = 4, KSy = 8;

  u8* wsb = (u8*)d_ws;
  size_t off = 0;
  auto alloc = [&](size_t n) { u8* p = wsb + off; off += (n + 63) & ~(size_t)63; return p; };

  u16* WtX = (u16*)alloc((size_t)512 * 512 * 2);
  u16* WtY = (u16*)alloc((size_t)512 * 256 * 2);
  u16* W2X = (u16*)alloc((size_t)128 * 256 * 2);
  u16* W2Y = (u16*)alloc((size_t)128 * 256 * 2);
  u8* B1x  = alloc((size_t)D1 * Nx);
  u8* B2x  = alloc((size_t)D1 * Ny);
  u8* B1y  = alloc((size_t)D1 * Ny);
  u8* B2y  = alloc((size_t)D1 * Nx);
  u16* x1  = (u16*)alloc((size_t)Nx * D1 * 2);
  u16* y1  = (u16*)alloc((size_t)Ny * D1 * 2);
  u8* B1x2 = alloc((size_t)C * Nx);
  u8* B2x2 = alloc((size_t)C * Ny);
  u8* B1y2 = alloc((size_t)C * Ny);
  u8* B2y2 = alloc((size_t)C * Nx);
  u16* x2  = (u16*)alloc((size_t)Nx * C * 2);
  u16* y2  = (u16*)alloc((size_t)Ny * C * 2);

  const size_t base_off = off;
  const size_t szHx1 = (size_t)Nx * Nx, szHx2 = (size_t)Nx * Ny;
  const size_t szHy1 = (size_t)Ny * Ny, szHy2 = (size_t)Ny * Nx;
  const size_t needA = base_off + szHx1 + szHx2 + szHy1 + szHy2 + ((size_t)32 << 20) + (1 << 20);

  u8 *hx1f8, *hx2f8, *hy1f8, *hy2f8; u16* part;
  if (ws_size >= needA) {
    hx1f8 = alloc(szHx1); hx2f8 = alloc(szHx2);
    hy1f8 = alloc(szHy1); hy2f8 = alloc(szHy2);
    part  = (u16*)alloc((size_t)32 << 20);
  } else {
    hy1f8 = alloc(szHy1); hy2f8 = alloc(szHy2);
    hx1f8 = (u8*)d_out;
    hx2f8 = (u8*)d_out + szHx1;
    part  = (u16*)((u8*)d_out + szHx1 + szHx2);
  }

  const size_t MNx1 = (size_t)Nx * D1, MNy1 = (size_t)Ny * D1;
  const size_t MNx2 = (size_t)Nx * C,  MNy2 = (size_t)Ny * C;
  u16* partY1 = part + (size_t)KSx * MNx1;
  u16* partY2 = part + 8 * MNx2;

  // 1) concat weights
  prep_w<<<dim3(256, 1, 8), 256, 0, stream>>>(Wx1a, Wx1b, Wy1a, Wy1b, Wx2a, Wx2b, Wy2a, Wy2b,
      WtX, WtY, W2X, W2Y, alphap, betap);

  // 2) layer-1 small GEMMs (merged x+y)
  gemmS_k<true><<<dim3(8, Nx/64 + Ny/64), 256, 0, stream>>>(
      x0, WtX, Fx, Nx, B1x, B2y,
      y0, WtY, Fy, Ny, B2x, B1y,
      Nx/64, 256, SB1);

  // 3) layer-1 FUSED big GEMMs, merged + balanced + depth-2-pairs pipeline
  gemmF_k<<<dim3(512), 1024, 0, stream>>>(
      hx1, hx2, B1x, B2x, hx1f8, hx2f8, Nx, Ny, Nx/KSx, Ny/KSx, part, MNx1,
      hy1, hy2, B1y, B2y, hy1f8, hy2f8, Ny, Nx, Ny/KSy, Nx/KSy, partY1, MNy1);

  // 4) merged layer-1 combine (x1 + y1)
  combine1_k<<<dim3(3072), 256, 0, stream>>>(part, partY1, 2048, MNx1, MNy1, KSx, KSy,
      bx1a, bx1b, alphap, by1a, by1b, betap, x1, y1, INV1);

  // 5) layer-2 small GEMMs (merged)
  gemmS_k<false><<<dim3(2, Nx/64 + Ny/64), 256, 0, stream>>>(
      x1, W2X, D1, Nx, B1x2, B2y2,
      y1, W2Y, D1, Ny, B2x2, B1y2,
      Nx/64, 64, SB2);

  // 6) layer-2 big GEMMs (merged + balanced)
  gemm8_k<<<dim3(1024), 256, 0, stream>>>(
      hx1f8, hx2f8, B1x2, B2x2, Nx, Ny, 1024, 512, part, MNx2,
      hy1f8, hy2f8, B1y2, B2y2, Ny, Nx, 256, 512, partY2, MNy2);

  // 7) FUSED layer-2 combine + log_softmax (x2 + x_output + y2)
  combine2_k<<<dim3(2048 + 1024), 256, 0, stream>>>(part, partY2, 2048, MNx2, MNy2,
      bx2a, bx2b, alphap, by2a, by2b, betap, x2, y2,
      (float*)d_out + (size_t)Nx * Ny, INV2);

  // 8) h_hat = sigmoid(x2 @ y2^T) -> d_out
  gemmH_k<<<dim3(Ny/128, Nx/128), 256, 0, stream>>>(x2, y2, C, (float*)d_out, Ny);
}

// Round 13
// 303.824 us; speedup vs baseline: 1.2333x; 1.2333x over previous
//
#include <hip/hip_runtime.h>

typedef unsigned short u16;
typedef unsigned char u8;
typedef long i64;
typedef __attribute__((ext_vector_type(8))) short bf16x8;
typedef __attribute__((ext_vector_type(4))) float f32x4;
typedef __attribute__((ext_vector_type(8))) u16 u16x8;
typedef __attribute__((ext_vector_type(4))) u16 u16x4;
typedef __attribute__((ext_vector_type(4))) float f4;

#define DEVI static __device__ __forceinline__

DEVI u16 f2b(float f) { __bf16 h = (__bf16)f; return __builtin_bit_cast(u16, h); }
DEVI float b2f(u16 h) { unsigned u = ((unsigned)h) << 16; return __builtin_bit_cast(float, u); }

DEVI int pk8(float a, float b, float c, float d) {
  int w = __builtin_amdgcn_cvt_pk_fp8_f32(a, b, 0, false);
  return __builtin_amdgcn_cvt_pk_fp8_f32(c, d, w, true);
}

DEVI void gload16(const void* g, void* l) {
  __builtin_amdgcn_global_load_lds((const __attribute__((address_space(1))) void*)g,
                                   (__attribute__((address_space(3))) void*)l, 16, 0, 0);
}

// ---------------------------------------------------------------------------
// MERGED fused layer-1 big GEMMs, ONE 512-block launch, dispatch-order
// balanced (R10) + TWO tiles per barrier (R11 -- best measured config).
// R12's depth-2 pipeline REGRESSED (+40% HBM traffic: in-flight working set
// 5.4MB/XCD > 4MiB L2 -> line re-fetch). Depth here is the L2-bounded optimum.
// Super-step: vmcnt(4) -> writeLDS(t,t+1) -> lgkmcnt(0) -> barrier ->
// loads(t+2,t+3) -> side-copy stores(t,t+1) -> compute(t,t+1).
// ---------------------------------------------------------------------------
__global__ __launch_bounds__(1024)
void gemmF_k(const float* __restrict__ xA0, const float* __restrict__ xA1,
             const u8* __restrict__ xB0, const u8* __restrict__ xB1,
             u8* __restrict__ xA0f8, u8* __restrict__ xA1f8,
             int xK0, int xK1, int xL0, int xL1, u16* __restrict__ xC, size_t xMN,
             const float* __restrict__ yA0, const float* __restrict__ yA1,
             const u8* __restrict__ yB0, const u8* __restrict__ yB1,
             u8* __restrict__ yA0f8, u8* __restrict__ yA1f8,
             int yK0, int yK1, int yL0, int yL1, u16* __restrict__ yC, size_t yMN)
{
  constexpr int BM = 128, BK = 64;
  constexpr int LDA = 72;
  constexpr int ASZ = BM * LDA;     // 9216
  constexpr int BSZ = 256 * BK;     // 16384
  constexpr int BUFSZ = ASZ + BSZ;  // 25600
  constexpr float SADJ = 8192.f;
  __shared__ __align__(16) u8 lds[4 * BUFSZ];   // 100 KiB -> 1 block/CU

  const int tid = threadIdx.x, lane = tid & 63, wave = tid >> 6;
  const int wm = (wave >> 2) * 32, wn = (wave & 3) * 64;   // 4x4 wave grid
  const int lgrp = lane >> 4, lrow = lane & 15;

  const int flat = blockIdx.x;                // 0..511

  const float *A0, *A1; const u8 *B0, *B1; u8 *A0f8, *A1f8;
  int K0, K1, L0, L1; u16* Cout; size_t MN; int m0, z;
  if (flat < 256) {                           // round 1: x on ALL CUs
    const int s = ((flat & 7) << 5) | (flat >> 3);   // XCD-chunked within x
    A0=xA0; A1=xA1; B0=xB0; B1=xB1; A0f8=xA0f8; A1f8=xA1f8;
    K0=xK0; K1=xK1; L0=xL0; L1=xL1; Cout=xC; MN=xMN;
    m0 = (s & 63) * BM; z = s >> 6;           // gy=64, z 0..3 (KSx=4)
  } else {                                    // round 2: y on ALL CUs
    const int f2 = flat - 256;
    const int s = ((f2 & 7) << 5) | (f2 >> 3);
    A0=yA0; A1=yA1; B0=yB0; B1=yB1; A0f8=yA0f8; A1f8=yA1f8;
    K0=yK0; K1=yK1; L0=yL0; L1=yL1; Cout=yC; MN=yMN;
    m0 = (s & 31) * BM; z = s >> 5;           // gy=32, z 0..7 (KSy=8)
  }

  const int nt0 = L0 >> 6, NT = nt0 + (L1 >> 6);   // 48 (x) / 24 (y), even

  const int r0 = tid >> 4;           // 0..63
  const int cf = (tid & 15) << 2;    // 0..60

  f32x4 acc[2][4];
#pragma unroll
  for (int m = 0; m < 2; ++m)
#pragma unroll
    for (int n = 0; n < 4; ++n) acc[m][n] = (f32x4){0.f, 0.f, 0.f, 0.f};

  f4 rA0[2], rA1[2];                 // two tile-parity register banks
  int pw0[2], pw1[2];                // packed fp8 words kept across rA refill

  auto tileinfo = [&](int t, const float*& Ap, const u8*& Bp, u8*& Af8, int& Kj, int& kk) {
    if (t < nt0) { Ap = A0; Bp = B0; Af8 = A0f8; Kj = K0; kk = z * L0 + (t << 6); }
    else         { Ap = A1; Bp = B1; Af8 = A1f8; Kj = K1; kk = z * L1 + ((t - nt0) << 6); }
  };

  auto loadA = [&](int t, f4 (&r)[2]) {
    const float* Ap; const u8* Bp; u8* Af8; int Kj, kk;
    tileinfo(t, Ap, Bp, Af8, Kj, kk);
#pragma unroll
    for (int j = 0; j < 2; ++j) {
      const int rr = j * 64 + r0;
      r[j] = __builtin_nontemporal_load(
          (const f4*)(Ap + (size_t)(m0 + rr) * Kj + kk + cf));
    }
  };

  auto loadB = [&](int t) {
    const float* Ap; const u8* Bp; u8* Af8; int Kj, kk;
    tileinfo(t, Ap, Bp, Af8, Kj, kk);
    u8* sB = &lds[(t & 3) * BUFSZ] + ASZ;
    const int off = tid * 16;
    const int r = off >> 6, c = off & 63;
    gload16(Bp + (size_t)r * Kj + kk + (c ^ (((r >> 1) & 3) << 4)), sB + off);
  };

  auto writeLDS = [&](int t, f4 (&r)[2], int (&pw)[2]) {   // cvt + ds_write only
    u8* sA = &lds[(t & 3) * BUFSZ];
#pragma unroll
    for (int j = 0; j < 2; ++j) {
      const int rr = j * 64 + r0;
      pw[j] = pk8(r[j][0] * SADJ, r[j][1] * SADJ, r[j][2] * SADJ, r[j][3] * SADJ);
      *(int*)&sA[rr * LDA + cf] = pw[j];
    }
  };

  auto storeCopy = [&](int t, int (&pw)[2]) {              // fp8 side-copy stores
    const float* Ap; const u8* Bp; u8* Af8; int Kj, kk;
    tileinfo(t, Ap, Bp, Af8, Kj, kk);
#pragma unroll
    for (int j = 0; j < 2; ++j) {
      const int rr = j * 64 + r0;
      *(int*)(Af8 + (size_t)(m0 + rr) * Kj + kk + cf) = pw[j];
    }
  };

  auto compute = [&](int t) {
    const u8* sA = &lds[(t & 3) * BUFSZ];
    const u8* sB = sA + ASZ;
    __builtin_amdgcn_s_setprio(1);
#pragma unroll
    for (int ks = 0; ks < 2; ++ks) {
      i64 a[2], b[4];
#pragma unroll
      for (int m = 0; m < 2; ++m) {
        const int r = wm + m * 16 + lrow;
        a[m] = *(const i64*)&sA[r * LDA + ks * 32 + lgrp * 8];
      }
#pragma unroll
      for (int n = 0; n < 4; ++n) {
        const int r = wn + n * 16 + lrow;
        b[n] = *(const i64*)&sB[r * BK + ((ks * 32 + lgrp * 8) ^ (((r >> 1) & 3) << 4))];
      }
#pragma unroll
      for (int m = 0; m < 2; ++m)
#pragma unroll
        for (int n = 0; n < 4; ++n)
          acc[m][n] = __builtin_amdgcn_mfma_f32_16x16x32_fp8_fp8(a[m], b[n], acc[m][n], 0, 0, 0);
    }
    __builtin_amdgcn_s_setprio(0);
  };

  // prologue: tiles 0,1 in flight (6 loads/thread)
  loadA(0, rA0); loadB(0);
  loadA(1, rA1); loadB(1);

  for (int t = 0; t < NT; t += 2) {
    // drain this pair's 6 loads; leave the previous pair's 4 stores aging
    if (t == 0) asm volatile("s_waitcnt vmcnt(0)" ::: "memory");
    else        asm volatile("s_waitcnt vmcnt(4)" ::: "memory");
    writeLDS(t, rA0, pw0);
    writeLDS(t + 1, rA1, pw1);
    asm volatile("s_waitcnt lgkmcnt(0)" ::: "memory");
    asm volatile("s_barrier" ::: "memory");          // ONE barrier per 2 tiles
    if (t + 2 < NT) { loadA(t + 2, rA0); loadB(t + 2); }   // bufs freed 2 barriers ago
    if (t + 3 < NT) { loadA(t + 3, rA1); loadB(t + 3); }
    storeCopy(t, pw0);                               // stores AFTER loads
    storeCopy(t + 1, pw1);
    compute(t);
    compute(t + 1);
  }

  u16* Cp = Cout + (size_t)z * MN;
#pragma unroll
  for (int n = 0; n < 4; ++n) {
    const int c = wn + n * 16 + lrow;
#pragma unroll
    for (int m = 0; m < 2; ++m) {
      const int rb = m0 + wm + m * 16 + lgrp * 4;
#pragma unroll
      for (int q = 0; q < 4; ++q)
        Cp[(size_t)(rb + q) * 256 + c] = f2b(acc[m][n][q]);
    }
  }
}

// ---------------------------------------------------------------------------
// MERGED fp8 layer-2 big GEMMs, ONE 1024-block launch (R10, unchanged).
// ---------------------------------------------------------------------------
__global__ __launch_bounds__(256)
void gemm8_k(const u8* __restrict__ xA0, const u8* __restrict__ xA1,
             const u8* __restrict__ xB0, const u8* __restrict__ xB1,
             int xK0, int xK1, int xL0, int xL1, u16* __restrict__ xC, size_t xMN,
             const u8* __restrict__ yA0, const u8* __restrict__ yA1,
             const u8* __restrict__ yB0, const u8* __restrict__ yB1,
             int yK0, int yK1, int yL0, int yL1, u16* __restrict__ yC, size_t yMN)
{
  constexpr int BM = 128, BK = 128, BN = 64;
  constexpr int MR = 4, NR = 2;
  constexpr int ASZ = BM * BK, BSZ = BN * BK;
  __shared__ __align__(16) u8 lds[3 * (ASZ + BSZ)];

  const int tid = threadIdx.x, lane = tid & 63, wave = tid >> 6;
  const int wm = (wave >> 1) * 64, wn = (wave & 1) * 32;
  const int lgrp = lane >> 4, lrow = lane & 15;

  const int flat = blockIdx.x;                // 0..1023

  const u8 *A0, *A1, *B0, *B1; int K0, K1, L0, L1; u16* Cw; size_t MN;
  int m0, z;
  if (flat < 512) {
    const int s = ((flat & 7) << 6) | (flat >> 3);
    A0=xA0; A1=xA1; B0=xB0; B1=xB1; K0=xK0; K1=xK1; L0=xL0; L1=xL1; Cw=xC; MN=xMN;
    m0 = (s & 63) * BM; z = s >> 6;
  } else {
    const int f2 = flat - 512;
    const int s = ((f2 & 7) << 6) | (f2 >> 3);
    A0=yA0; A1=yA1; B0=yB0; B1=yB1; K0=yK0; K1=yK1; L0=yL0; L1=yL1; Cw=yC; MN=yMN;
    m0 = (s & 31) * BM; z = s >> 5;
  }

  const int nt0 = L0 >> 7, NT = nt0 + (L1 >> 7);

  f32x4 acc[MR][NR];
#pragma unroll
  for (int m = 0; m < MR; ++m)
#pragma unroll
    for (int n = 0; n < NR; ++n) acc[m][n] = (f32x4){0.f, 0.f, 0.f, 0.f};

  auto stage = [&](int buf, int t) {
    const u8* Ap; const u8* Bp; int Kj, kk;
    if (t < nt0) { Ap = A0; Bp = B0; Kj = K0; kk = z * L0 + (t << 7); }
    else         { Ap = A1; Bp = B1; Kj = K1; kk = z * L1 + ((t - nt0) << 7); }
    u8* sA = &lds[buf * (ASZ + BSZ)];
    u8* sB = sA + ASZ;
#pragma unroll
    for (int i = 0; i < ASZ / 4096; ++i) {
      const int off = i * 4096 + tid * 16;
      const int r = off >> 7, c = off & 127;
      gload16(Ap + (size_t)(m0 + r) * Kj + kk + (c ^ ((r & 7) << 4)), sA + off);
    }
#pragma unroll
    for (int i = 0; i < BSZ / 4096; ++i) {
      const int off = i * 4096 + tid * 16;
      const int r = off >> 7, c = off & 127;
      gload16(Bp + (size_t)r * Kj + kk + (c ^ ((r & 7) << 4)), sB + off);
    }
  };

  auto compute = [&](int buf) {
    const u8* sA = &lds[buf * (ASZ + BSZ)];
    const u8* sB = sA + ASZ;
    __builtin_amdgcn_s_setprio(1);
#pragma unroll
    for (int ks = 0; ks < 4; ++ks) {
      i64 a[MR], b[NR];
#pragma unroll
      for (int m = 0; m < MR; ++m) {
        const int r = wm + m * 16 + lrow;
        a[m] = *(const i64*)&sA[r * BK + ((ks * 32 + lgrp * 8) ^ ((r & 7) << 4))];
      }
#pragma unroll
      for (int n = 0; n < NR; ++n) {
        const int r = wn + n * 16 + lrow;
        b[n] = *(const i64*)&sB[r * BK + ((ks * 32 + lgrp * 8) ^ ((r & 7) << 4))];
      }
#pragma unroll
      for (int m = 0; m < MR; ++m)
#pragma unroll
        for (int n = 0; n < NR; ++n)
          acc[m][n] = __builtin_amdgcn_mfma_f32_16x16x32_fp8_fp8(a[m], b[n], acc[m][n], 0, 0, 0);
    }
    __builtin_amdgcn_s_setprio(0);
  };

  stage(0, 0);
  stage(1, 1);
  for (int t = 0; t < NT; ++t) {
    if (t + 1 < NT) asm volatile("s_waitcnt vmcnt(6)" ::: "memory");
    else            asm volatile("s_waitcnt vmcnt(0)" ::: "memory");
    asm volatile("s_barrier" ::: "memory");
    compute(t % 3);
    if (t + 2 < NT) stage((t + 2) % 3, t + 2);
  }

  u16* Cp = Cw + (size_t)z * MN;
#pragma unroll
  for (int n = 0; n < NR; ++n) {
    const int c = wn + n * 16 + lrow;
#pragma unroll
    for (int m = 0; m < MR; ++m) {
      const int rb = m0 + wm + m * 16 + lgrp * 4;
#pragma unroll
      for (int q = 0; q < 4; ++q)
        Cp[(size_t)(rb + q) * 64 + c] = f2b(acc[m][n][q]);
    }
  }
}

// ---------------------------------------------------------------------------
// MERGED dual-problem small GEMM (unchanged).
// ---------------------------------------------------------------------------
template<bool A_F32>
__global__ __launch_bounds__(256)
void gemmS_k(const void* Ax, const u16* Bx, int Kx, int ldcx, u8* Cx1, u8* Cx2,
             const void* Ay, const u16* By, int Ky, int ldcy, u8* Cy1, u8* Cy2,
             int ySplit, int nsplit, float sOut)
{
  constexpr int BM = 64, BN = 64, BK = 32, LD = 40;
  constexpr int MR = 2, NR = 2;
  __shared__ u16 sA[BM * LD];
  __shared__ u16 sB[BN * LD];

  const int tid  = threadIdx.x;
  const int lane = tid & 63;
  const int wave = tid >> 6;
  const int wm = (wave >> 1) * 32;
  const int wn = (wave &  1) * 32;

  const void* A0_; const u16* B0_; int K0, ldc; u8 *C1, *C2; int m0;
  if ((int)blockIdx.y < ySplit) {
    A0_ = Ax; B0_ = Bx; K0 = Kx; ldc = ldcx; C1 = Cx1; C2 = Cx2;
    m0 = blockIdx.y * BM;
  } else {
    A0_ = Ay; B0_ = By; K0 = Ky; ldc = ldcy; C1 = Cy1; C2 = Cy2;
    m0 = (blockIdx.y - ySplit) * BM;
  }
  const int n0 = blockIdx.x * BN;

  constexpr int TPRA = 256 / BM;
  constexpr int EPTA = 32 / TPRA;
  const int ar = tid / TPRA, ac = (tid % TPRA) * EPTA;
  const int br = ar, bc = ac;

  f32x4 acc[MR][NR];
#pragma unroll
  for (int m = 0; m < MR; ++m)
#pragma unroll
    for (int n = 0; n < NR; ++n) acc[m][n] = (f32x4){0.f, 0.f, 0.f, 0.f};

  const int lgrp = lane >> 4, lrow = lane & 15;

  for (int kk = 0; kk < K0; kk += BK) {
    if constexpr (A_F32) {
      const float* Ap = (const float*)A0_ + (size_t)(m0 + ar) * K0 + kk + ac;
      f4 v0 = ((const f4*)Ap)[0];
      f4 v1 = ((const f4*)Ap)[1];
      u16x8 h;
      h[0]=f2b(v0[0]); h[1]=f2b(v0[1]); h[2]=f2b(v0[2]); h[3]=f2b(v0[3]);
      h[4]=f2b(v1[0]); h[5]=f2b(v1[1]); h[6]=f2b(v1[2]); h[7]=f2b(v1[3]);
      *(u16x8*)&sA[ar * LD + ac] = h;
    } else {
      const u16* Ap = (const u16*)A0_ + (size_t)(m0 + ar) * K0 + kk + ac;
      *(u16x8*)&sA[ar * LD + ac] = *(const u16x8*)Ap;
    }
    {
      const u16* Bp = B0_ + (size_t)(n0 + br) * K0 + kk + bc;
      *(u16x8*)&sB[br * LD + bc] = *(const u16x8*)Bp;
    }
    __syncthreads();
    bf16x8 af[MR], bfr[NR];
#pragma unroll
    for (int m = 0; m < MR; ++m)
      af[m] = *(const bf16x8*)&sA[(wm + m * 16 + lrow) * LD + lgrp * 8];
#pragma unroll
    for (int n = 0; n < NR; ++n)
      bfr[n] = *(const bf16x8*)&sB[(wn + n * 16 + lrow) * LD + lgrp * 8];
#pragma unroll
    for (int m = 0; m < MR; ++m)
#pragma unroll
      for (int n = 0; n < NR; ++n)
        acc[m][n] = __builtin_amdgcn_mfma_f32_16x16x32_bf16(af[m], bfr[n], acc[m][n], 0, 0, 0);
    __syncthreads();
  }

#pragma unroll
  for (int n = 0; n < NR; ++n) {
    const int c = n0 + wn + n * 16 + lrow;
    u8* Cp = (c < nsplit) ? C1 : C2;
    const int cr = (c < nsplit) ? c : c - nsplit;
#pragma unroll
    for (int m = 0; m < MR; ++m) {
      const int rb = m0 + wm + m * 16 + lgrp * 4;
      int w = __builtin_amdgcn_cvt_pk_fp8_f32(acc[m][n][0] * sOut, acc[m][n][1] * sOut, 0, false);
      w = __builtin_amdgcn_cvt_pk_fp8_f32(acc[m][n][2] * sOut, acc[m][n][3] * sOut, w, true);
      *(int*)&Cp[(size_t)cr * ldc + rb] = w;
    }
  }
}

// ---------------------------------------------------------------------------
// bf16 GEMM for h_hat: sigmoid -> f32 row-major, nontemporal stores (unchanged).
// ---------------------------------------------------------------------------
__global__ __launch_bounds__(256)
void gemmH_k(const u16* A0_, const u16* B0_, int K0, float* Cout, int ldc)
{
  constexpr int BM = 128, BN = 128, BK = 32, LD = 40;
  constexpr int MR = 4, NR = 4;
  __shared__ u16 sA[BM * LD];
  __shared__ u16 sB[BN * LD];

  const int tid  = threadIdx.x;
  const int lane = tid & 63;
  const int wave = tid >> 6;
  const int wm = (wave >> 1) * 64;
  const int wn = (wave &  1) * 64;
  const int m0 = blockIdx.y * BM;
  const int n0 = blockIdx.x * BN;

  constexpr int TPRA = 2;
  constexpr int EPTA = 16;
  const int ar = tid / TPRA, ac = (tid % TPRA) * EPTA;

  f32x4 acc[MR][NR];
#pragma unroll
  for (int m = 0; m < MR; ++m)
#pragma unroll
    for (int n = 0; n < NR; ++n) acc[m][n] = (f32x4){0.f, 0.f, 0.f, 0.f};

  const int lgrp = lane >> 4, lrow = lane & 15;

  for (int kk = 0; kk < K0; kk += BK) {
    {
      const u16* Ap = A0_ + (size_t)(m0 + ar) * K0 + kk + ac;
      *(u16x8*)&sA[ar * LD + ac]     = ((const u16x8*)Ap)[0];
      *(u16x8*)&sA[ar * LD + ac + 8] = ((const u16x8*)Ap)[1];
      const u16* Bp = B0_ + (size_t)(n0 + ar) * K0 + kk + ac;
      *(u16x8*)&sB[ar * LD + ac]     = ((const u16x8*)Bp)[0];
      *(u16x8*)&sB[ar * LD + ac + 8] = ((const u16x8*)Bp)[1];
    }
    __syncthreads();
    bf16x8 af[MR], bfr[NR];
#pragma unroll
    for (int m = 0; m < MR; ++m)
      af[m] = *(const bf16x8*)&sA[(wm + m * 16 + lrow) * LD + lgrp * 8];
#pragma unroll
    for (int n = 0; n < NR; ++n)
      bfr[n] = *(const bf16x8*)&sB[(wn + n * 16 + lrow) * LD + lgrp * 8];
#pragma unroll
    for (int m = 0; m < MR; ++m)
#pragma unroll
      for (int n = 0; n < NR; ++n)
        acc[m][n] = __builtin_amdgcn_mfma_f32_16x16x32_bf16(af[m], bfr[n], acc[m][n], 0, 0, 0);
    __syncthreads();
  }

  float* Cp = Cout;
#pragma unroll
  for (int n = 0; n < NR; ++n) {
    const int c = n0 + wn + n * 16 + lrow;
#pragma unroll
    for (int m = 0; m < MR; ++m) {
      const int rb = m0 + wm + m * 16 + lgrp * 4;
#pragma unroll
      for (int q = 0; q < 4; ++q)
        __builtin_nontemporal_store(1.f / (1.f + __expf(-acc[m][n][q])),
                                    &Cp[(size_t)(rb + q) * ldc + c]);
    }
  }
}

// ---------------------------------------------------------------------------
// MERGED layer-1 combine (unchanged).
// ---------------------------------------------------------------------------
__global__ __launch_bounds__(256)
void combine1_k(const u16* __restrict__ partX, const u16* __restrict__ partY,
                int xBlocks, size_t MNx, size_t MNy, int KSx_, int KSy_,
                const float* bxa, const float* bxb, const float* ap,
                const float* bya, const float* byb, const float* bp,
                u16* x1, u16* y1, float invs)
{
  const u16* parts; size_t MN; int KS, nb, bid = blockIdx.x;
  const float *b0, *b1, *mixp; u16* out;
  if (bid < xBlocks) {
    parts = partX; MN = MNx; KS = KSx_; b0 = bxa; b1 = bxb; mixp = ap; out = x1; nb = xBlocks;
  } else {
    bid -= xBlocks;
    parts = partY; MN = MNy; KS = KSy_; b0 = bya; b1 = byb; mixp = bp; out = y1;
    nb = gridDim.x - xBlocks;
  }
  const float mix = *mixp;
  const size_t stride = (size_t)nb * 1024;
  for (size_t i = ((size_t)bid * 256 + threadIdx.x) * 4; i < MN; i += stride) {
    f4 s = {0.f, 0.f, 0.f, 0.f};
    for (int zz = 0; zz < KS; ++zz) {
      u16x4 pv = *(const u16x4*)&parts[(size_t)zz * MN + i];
#pragma unroll
      for (int q = 0; q < 4; ++q) s[q] += b2f(pv[q]);
    }
    const int c = (int)(i & 255);          // N = 256
    u16x4 o;
#pragma unroll
    for (int q = 0; q < 4; ++q) {
      float v = s[q] * invs + mix * b0[c + q] + (1.f - mix) * b1[c + q];
      v = v >= 0.f ? v : 0.2f * v;
      o[q] = f2b(v);
    }
    *(u16x4*)&out[i] = o;
  }
}

// ---------------------------------------------------------------------------
// FUSED layer-2 combine + log_softmax (unchanged).
// ---------------------------------------------------------------------------
__global__ __launch_bounds__(256)
void combine2_k(const u16* __restrict__ partX, const u16* __restrict__ partY,
                int xRowBlocks, size_t MNx, size_t MNy,
                const float* bxa, const float* bxb, const float* ap,
                const float* bya, const float* byb, const float* bp,
                u16* x2, u16* y2, float* xout, float invs)
{
  const int w = threadIdx.x >> 6, lane = threadIdx.x & 63;
  if ((int)blockIdx.x < xRowBlocks) {
    const int row = blockIdx.x * 4 + w;
    const float a = *ap;
    float s = 0.f;
#pragma unroll
    for (int z = 0; z < 8; ++z)
      s += b2f(partX[(size_t)z * MNx + (size_t)row * 64 + lane]);
    float v = s * invs + a * bxa[lane] + (1.f - a) * bxb[lane];
    v = v >= 0.f ? v : 0.2f * v;
    x2[(size_t)row * 64 + lane] = f2b(v);
    float m = v;
#pragma unroll
    for (int o = 32; o; o >>= 1) m = fmaxf(m, __shfl_xor(m, o));
    float t = __expf(v - m);
#pragma unroll
    for (int o = 32; o; o >>= 1) t += __shfl_xor(t, o);
    xout[(size_t)row * 64 + lane] = v - m - __logf(t);
  } else {
    const int row = ((int)blockIdx.x - xRowBlocks) * 4 + w;
    const float b = *bp;
    float s = 0.f;
#pragma unroll
    for (int z = 0; z < 16; ++z)
      s += b2f(partY[(size_t)z * MNy + (size_t)row * 64 + lane]);
    float v = s * invs + b * bya[lane] + (1.f - b) * byb[lane];
    v = v >= 0.f ? v : 0.2f * v;
    y2[(size_t)row * 64 + lane] = f2b(v);
  }
}

// Concatenated transposed scaled bf16 weights (unchanged)
__global__ __launch_bounds__(256)
void prep_w(const float* Wx1a, const float* Wx1b, const float* Wy1a, const float* Wy1b,
            const float* Wx2a, const float* Wx2b, const float* Wy2a, const float* Wy2b,
            u16* WtX, u16* WtY, u16* W2X, u16* W2Y,
            const float* ap, const float* bp)
{
  const int zz = blockIdx.z;
  const float a = *ap, b = *bp;
  const float* W; u16* O; int K, N, roff; float s;
  switch (zz) {
    case 0: W=Wx1a; O=WtX; K=512; N=256; roff=0;   s=a;      break;
    case 1: W=Wy1b; O=WtX; K=512; N=256; roff=256; s=1.f-b;  break;
    case 2: W=Wx1b; O=WtY; K=256; N=256; roff=0;   s=1.f-a;  break;
    case 3: W=Wy1a; O=WtY; K=256; N=256; roff=256; s=b;      break;
    case 4: W=Wx2a; O=W2X; K=256; N=64;  roff=0;   s=a;      break;
    case 5: W=Wy2b; O=W2X; K=256; N=64;  roff=64;  s=1.f-b;  break;
    case 6: W=Wx2b; O=W2Y; K=256; N=64;  roff=0;   s=1.f-a;  break;
    default:W=Wy2a; O=W2Y; K=256; N=64;  roff=64;  s=b;      break;
  }
  const int total = K * N;
  for (int i = blockIdx.x * 256 + threadIdx.x; i < total; i += gridDim.x * 256) {
    const int k = i / N, n = i - k * N;
    O[(size_t)(n + roff) * K + k] = f2b(W[i] * s);
  }
}

extern "C" void kernel_launch(void* const* d_in, const int* in_sizes, int n_in,
                              void* d_out, int out_size, void* d_ws, size_t ws_size,
                              hipStream_t stream)
{
  const float* hx1 = (const float*)d_in[0];
  const float* hx2 = (const float*)d_in[1];
  const float* x0  = (const float*)d_in[2];
  const float* hy1 = (const float*)d_in[3];
  const float* hy2 = (const float*)d_in[4];
  const float* y0  = (const float*)d_in[5];
  const float* alphap = (const float*)d_in[6];
  const float* betap  = (const float*)d_in[7];
  const float* Wx1a = (const float*)d_in[8];  const float* bx1a = (const float*)d_in[9];
  const float* Wx1b = (const float*)d_in[10]; const float* bx1b = (const float*)d_in[11];
  const float* Wx2a = (const float*)d_in[12]; const float* bx2a = (const float*)d_in[13];
  const float* Wx2b = (const float*)d_in[14]; const float* bx2b = (const float*)d_in[15];
  const float* Wy1a = (const float*)d_in[16]; const float* by1a = (const float*)d_in[17];
  const float* Wy1b = (const float*)d_in[18]; const float* by1b = (const float*)d_in[19];
  const float* Wy2a = (const float*)d_in[20]; const float* by2a = (const float*)d_in[21];
  const float* Wy2b = (const float*)d_in[22]; const float* by2b = (const float*)d_in[23];
  (void)in_sizes; (void)n_in; (void)out_size;

  constexpr int Nx = 8192, Ny = 4096, Fx = 512, Fy = 256, D1 = 256, C = 64;
  constexpr float SB1 = 16.f, SB2 = 256.f;
  constexpr float INV1 = 1.f / (8192.f * 16.f);
  constexpr float INV2 = 1.f / (8192.f * 256.f);
  constexpr int KSx = 4, KSy = 8;

  u8* wsb = (u8*)d_ws;
  size_t off = 0;
  auto alloc = [&](size_t n) { u8* p = wsb + off; off += (n + 63) & ~(size_t)63; return p; };

  u16* WtX = (u16*)alloc((size_t)512 * 512 * 2);
  u16* WtY = (u16*)alloc((size_t)512 * 256 * 2);
  u16* W2X = (u16*)alloc((size_t)128 * 256 * 2);
  u16* W2Y = (u16*)alloc((size_t)128 * 256 * 2);
  u8* B1x  = alloc((size_t)D1 * Nx);
  u8* B2x  = alloc((size_t)D1 * Ny);
  u8* B1y  = alloc((size_t)D1 * Ny);
  u8* B2y  = alloc((size_t)D1 * Nx);
  u16* x1  = (u16*)alloc((size_t)Nx * D1 * 2);
  u16* y1  = (u16*)alloc((size_t)Ny * D1 * 2);
  u8* B1x2 = alloc((size_t)C * Nx);
  u8* B2x2 = alloc((size_t)C * Ny);
  u8* B1y2 = alloc((size_t)C * Ny);
  u8* B2y2 = alloc((size_t)C * Nx);
  u16* x2  = (u16*)alloc((size_t)Nx * C * 2);
  u16* y2  = (u16*)alloc((size_t)Ny * C * 2);

  const size_t base_off = off;
  const size_t szHx1 = (size_t)Nx * Nx, szHx2 = (size_t)Nx * Ny;
  const size_t szHy1 = (size_t)Ny * Ny, szHy2 = (size_t)Ny * Nx;
  const size_t needA = base_off + szHx1 + szHx2 + szHy1 + szHy2 + ((size_t)32 << 20) + (1 << 20);

  u8 *hx1f8, *hx2f8, *hy1f8, *hy2f8; u16* part;
  if (ws_size >= needA) {
    hx1f8 = alloc(szHx1); hx2f8 = alloc(szHx2);
    hy1f8 = alloc(szHy1); hy2f8 = alloc(szHy2);
    part  = (u16*)alloc((size_t)32 << 20);
  } else {
    hy1f8 = alloc(szHy1); hy2f8 = alloc(szHy2);
    hx1f8 = (u8*)d_out;
    hx2f8 = (u8*)d_out + szHx1;
    part  = (u16*)((u8*)d_out + szHx1 + szHx2);
  }

  const size_t MNx1 = (size_t)Nx * D1, MNy1 = (size_t)Ny * D1;
  const size_t MNx2 = (size_t)Nx * C,  MNy2 = (size_t)Ny * C;
  u16* partY1 = part + (size_t)KSx * MNx1;
  u16* partY2 = part + 8 * MNx2;

  // 1) concat weights
  prep_w<<<dim3(256, 1, 8), 256, 0, stream>>>(Wx1a, Wx1b, Wy1a, Wy1b, Wx2a, Wx2b, Wy2a, Wy2b,
      WtX, WtY, W2X, W2Y, alphap, betap);

  // 2) layer-1 small GEMMs (merged x+y)
  gemmS_k<true><<<dim3(8, Nx/64 + Ny/64), 256, 0, stream>>>(
      x0, WtX, Fx, Nx, B1x, B2y,
      y0, WtY, Fy, Ny, B2x, B1y,
      Nx/64, 256, SB1);

  // 3) layer-1 FUSED big GEMMs, merged + balanced + 2-tiles-per-barrier (R11)
  gemmF_k<<<dim3(512), 1024, 0, stream>>>(
      hx1, hx2, B1x, B2x, hx1f8, hx2f8, Nx, Ny, Nx/KSx, Ny/KSx, part, MNx1,
      hy1, hy2, B1y, B2y, hy1f8, hy2f8, Ny, Nx, Ny/KSy, Nx/KSy, partY1, MNy1);

  // 4) merged layer-1 combine (x1 + y1)
  combine1_k<<<dim3(3072), 256, 0, stream>>>(part, partY1, 2048, MNx1, MNy1, KSx, KSy,
      bx1a, bx1b, alphap, by1a, by1b, betap, x1, y1, INV1);

  // 5) layer-2 small GEMMs (merged)
  gemmS_k<false><<<dim3(2, Nx/64 + Ny/64), 256, 0, stream>>>(
      x1, W2X, D1, Nx, B1x2, B2y2,
      y1, W2Y, D1, Ny, B2x2, B1y2,
      Nx/64, 64, SB2);

  // 6) layer-2 big GEMMs (merged + balanced)
  gemm8_k<<<dim3(1024), 256, 0, stream>>>(
      hx1f8, hx2f8, B1x2, B2x2, Nx, Ny, 1024, 512, part, MNx2,
      hy1f8, hy2f8, B1y2, B2y2, Ny, Nx, 256, 512, partY2, MNy2);

  // 7) FUSED layer-2 combine + log_softmax (x2 + x_output + y2)
  combine2_k<<<dim3(2048 + 1024), 256, 0, stream>>>(part, partY2, 2048, MNx2, MNy2,
      bx2a, bx2b, alphap, by2a, by2b, betap, x2, y2,
      (float*)d_out + (size_t)Nx * Ny, INV2);

  // 8) h_hat = sigmoid(x2 @ y2^T) -> d_out
  gemmH_k<<<dim3(Ny/128, Nx/128), 256, 0, stream>>>(x2, y2, C, (float*)d_out, Ny);
}